// Round 8
// baseline (1937.074 us; speedup 1.0000x reference)
//
#include <hip/hip_runtime.h>
#include <hip/hip_bf16.h>

typedef unsigned short u16;
typedef unsigned int   u32;
typedef _Float16 h2 __attribute__((ext_vector_type(2)));

#define N_NODES 50000
#define N_EDGES 800000

// ---- ws layout (u32/float units) ---- (identical to R6)
#define OFF_WBUF  0          // 11,080 floats reserved
#define OFF_SP16  11080      // 800,000 u16 = 400,000 u32
#define OFF_VP16  411080     // 2,400,000 u16 = 1,200,000 u32
#define IDX_DEG   1611080    // 50,000 int
#define IDX_OFFS  1661080    // 50,001 int
#define IDX_CURS  1711088    // 50,000 int
#define IDX_PERM  1761088    // 800,000 records x 8 u32 -> ends 8,161,088 (32.6 MB)

// wbuf internal offsets (float units)
#define WB_W1H  0      // [64][4] u32 half2: (W1[2ip][j], W1[2ip+1][j])
#define WB_B1   256    // [64] f32
#define WB_W2H  320    // [80][32] u32 half2: w2h[o*32+jp] = (W2[2jp][o], W2[2jp+1][o])
#define WB_WINS 2880
#define WB_WINV 3136
#define WB_WOS  3392
#define WB_WOV  4416
#define WB_SCS  5184
#define WB_SCV  7232
#define WB_FLAG 8256

#define RPB  48     // receivers per block (bins 34KB + weights 11.5KB -> 3 blocks/CU)
#define BINW 177    // 176 accum + 1 pad
#define NWU  2880   // u32 words of weights staged to LDS (covers W1H|B1|W2H)

__device__ __forceinline__ float bf2f(u16 v){
  union { u32 u; float f; } x; x.u = ((u32)v) << 16; return x.f;
}
__device__ __forceinline__ u16 f2bf(float f){
  u32 u = __float_as_uint(f);
  u32 lsb = (u >> 16) & 1u;
  u32 r = u + 0x7fffu + lsb;
  return (u16)(r >> 16);
}
__device__ __forceinline__ float ldx(const void* p, long long i, int isf){
  return isf ? ((const float*)p)[i] : bf2f(((const u16*)p)[i]);
}
__device__ __forceinline__ u32 pk2(float a, float b){
  return (u32)f2bf(a) | ((u32)f2bf(b) << 16);
}
__device__ __forceinline__ u32 pkh2(float a, float b){
  union { u32 u; h2 v; } x; x.v.x = (_Float16)a; x.v.y = (_Float16)b; return x.u;
}
__device__ __forceinline__ float dot2(h2 a, u32 w, float c){
  union { u32 u; h2 v; } x; x.u = w;
#if __has_builtin(__builtin_amdgcn_fdot2)
  return __builtin_amdgcn_fdot2(a, x.v, c, false);
#else
  return c + (float)a.x*(float)x.v.x + (float)a.y*(float)x.v.y;
#endif
}
__device__ __forceinline__ float sigmoidf_(float x){ return 1.f/(1.f + __expf(-x)); }

__global__ void detect_dtype(const u32* __restrict__ remb_raw, int* __restrict__ flag){
  int isf32 = 0;
  for (int k = 0; k < 64; k++){
    u32 w = remb_raw[k];
    u32 lo = w & 0xffffu, hi = w >> 16;
    int okl = ((lo & 0x8000u) == 0) && (((lo >> 7) & 0xffu) <= 126u);
    int okh = ((hi & 0x8000u) == 0) && (((hi >> 7) & 0xffu) <= 126u);
    if (!(okl && okh)) isf32 = 1;
  }
  *flag = isf32;
}

__global__ void prep_weights(const void* __restrict__ w1, const void* __restrict__ b1g,
                             const void* __restrict__ w2, const void* __restrict__ wins,
                             const void* __restrict__ winv, const void* __restrict__ wos,
                             const void* __restrict__ wov, const void* __restrict__ scs,
                             const void* __restrict__ scv, float* __restrict__ wbuf,
                             const int* __restrict__ flag){
  int t = threadIdx.x;
  int isf = *flag;
  u32* w1h = (u32*)(wbuf + WB_W1H);
  u32* w2h = (u32*)(wbuf + WB_W2H);
  for (int idx=t; idx<256;  idx+=256){
    int j = idx>>2, ip = idx&3;
    w1h[idx] = pkh2(ldx(w1, (2*ip)*64+j, isf), ldx(w1, (2*ip+1)*64+j, isf));
  }
  for (int idx=t; idx<64;   idx+=256){ wbuf[WB_B1+idx]  = ldx(b1g, idx, isf); }
  for (int idx=t; idx<2560; idx+=256){
    int o = idx>>5, jp = idx&31;
    w2h[idx] = pkh2(ldx(w2, (2*jp)*80+o, isf), ldx(w2, (2*jp+1)*80+o, isf));
  }
  for (int idx=t; idx<256;  idx+=256){ wbuf[WB_WINS+idx] = ldx(wins, idx, isf); }
  for (int idx=t; idx<256;  idx+=256){ wbuf[WB_WINV+idx] = ldx(winv, idx, isf); }
  for (int idx=t; idx<1024; idx+=256){ wbuf[WB_WOS+idx]  = ldx(wos, idx, isf); }
  for (int idx=t; idx<768;  idx+=256){ wbuf[WB_WOV+idx]  = ldx(wov, idx, isf); }
  for (int idx=t; idx<2048; idx+=256){ wbuf[WB_SCS+idx]  = ldx(scs, idx, isf); }
  for (int idx=t; idx<1024; idx+=256){ wbuf[WB_SCV+idx]  = ldx(scv, idx, isf); }
}

__global__ void node_pre(const void* __restrict__ ns_g, const void* __restrict__ nv_g,
                         const float* __restrict__ wbuf, u16* __restrict__ sp16,
                         u16* __restrict__ vp16, const int* __restrict__ flag){
  int n = blockIdx.x*256 + threadIdx.x;
  if (n >= N_NODES) return;
  int isf = *flag;
  float a[16], b[48];
  #pragma unroll
  for (int u=0;u<16;u++) a[u] = ldx(ns_g, n*16+u, isf);
  #pragma unroll
  for (int u=0;u<48;u++) b[u] = ldx(nv_g, n*48+u, isf);

  const float* wins = wbuf + WB_WINS;
  const float* winv = wbuf + WB_WINV;
  float s[16];
  #pragma unroll
  for (int w=0;w<16;w++) s[w]=0.f;
  #pragma unroll
  for (int u=0;u<16;u++){
    float au = a[u];
    #pragma unroll
    for (int w=0;w<16;w++) s[w] += au * wins[u*16+w];
  }
  #pragma unroll
  for (int w=0;w<16;w++) sp16[n*16+w] = f2bf(s[w]);
  float v0[16], v1[16], v2[16];
  #pragma unroll
  for (int w=0;w<16;w++){ v0[w]=0.f; v1[w]=0.f; v2[w]=0.f; }
  #pragma unroll
  for (int u=0;u<16;u++){
    float bu0=b[u*3], bu1=b[u*3+1], bu2=b[u*3+2];
    #pragma unroll
    for (int w=0;w<16;w++){
      float wv = winv[u*16+w];
      v0[w] += bu0*wv; v1[w] += bu1*wv; v2[w] += bu2*wv;
    }
  }
  #pragma unroll
  for (int w=0;w<16;w++){
    vp16[n*48+w*3]   = f2bf(v0[w]);
    vp16[n*48+w*3+1] = f2bf(v1[w]);
    vp16[n*48+w*3+2] = f2bf(v2[w]);
  }
}

__global__ void count_edges(const int* __restrict__ receivers, int* __restrict__ deg){
  int e = blockIdx.x*256 + threadIdx.x;
  if (e < N_EDGES) atomicAdd(&deg[receivers[e]], 1);
}

__global__ void scan_offsets(const int* __restrict__ deg, int* __restrict__ offs,
                             int* __restrict__ curs){
  __shared__ int part[1024];
  int t = threadIdx.x;
  const int PER = 49;
  int base = t*PER;
  int s = 0;
  for (int i=0;i<PER;i++){ int n=base+i; if (n<N_NODES) s += deg[n]; }
  part[t] = s; __syncthreads();
  for (int off=1; off<1024; off<<=1){
    int v = (t>=off) ? part[t-off] : 0;
    __syncthreads(); part[t] += v; __syncthreads();
  }
  int run = (t==0) ? 0 : part[t-1];
  for (int i=0;i<PER;i++){
    int n=base+i;
    if (n<N_NODES){ offs[n]=run; curs[n]=run; run += deg[n]; }
  }
  if (t==1023) offs[N_NODES] = run;
}

// permute edge data into receiver-sorted order as packed 32B bf16 records
__global__ void fill_perm(const void* __restrict__ edge_sh, const void* __restrict__ remb,
                          const int* __restrict__ senders, const int* __restrict__ receivers,
                          int* __restrict__ curs, u32* __restrict__ perm,
                          const int* __restrict__ flag){
  int e = blockIdx.x*256 + threadIdx.x;
  if (e >= N_EDGES) return;
  int isf = *flag;
  float sh0 = ldx(edge_sh, (long long)e*4+0, isf);
  float sh1 = ldx(edge_sh, (long long)e*4+1, isf);
  float sh2 = ldx(edge_sh, (long long)e*4+2, isf);
  float sh3 = ldx(edge_sh, (long long)e*4+3, isf);
  float re[8];
  #pragma unroll
  for (int i=0;i<8;i++) re[i] = ldx(remb, (long long)e*8+i, isf);
  int snd = senders[e], rcv = receivers[e];
  int p = atomicAdd(&curs[rcv], 1);
  u32* rec = perm + (size_t)p*8;
  uint4 r0, r1;
  r0.x = pk2(sh0, sh1);   r0.y = pk2(sh2, sh3);
  r0.z = pk2(re[0], re[1]); r0.w = pk2(re[2], re[3]);
  r1.x = pk2(re[4], re[5]); r1.y = pk2(re[6], re[7]);
  r1.z = (u32)snd; r1.w = (u32)rcv;
  *reinterpret_cast<uint4*>(rec)     = r0;
  *reinterpret_cast<uint4*>(rec + 4) = r1;
}

// thread-per-edge (coalesced stream), LDS-resident fp16 weights (broadcast ds_read),
// LDS bins, fused epilogue.  Structure identical to R6 except weight source.
__global__ void __launch_bounds__(256, 3) fused_gather(
    const u32* __restrict__ perm, const int* __restrict__ offs,
    const u16* __restrict__ sp16, const u16* __restrict__ vp16,
    const void* __restrict__ ns_g, const void* __restrict__ nv_g,
    const int* __restrict__ species, const float* __restrict__ wbuf,
    void* __restrict__ out, const int* __restrict__ flag){
  __shared__ float bins[RPB * BINW];   // 34.0 KB
  __shared__ u32   lw[NWU];            // 11.5 KB: W1H | B1 | W2H
  int tid = threadIdx.x;
  int r0 = blockIdx.x * RPB;
  int rEnd = min(r0 + RPB, N_NODES);
  int isf = *flag;

  for (int i = tid; i < RPB*BINW; i += 256) bins[i] = 0.f;
  {
    const u32* wsrc = (const u32*)wbuf;
    for (int i = tid; i < NWU; i += 256) lw[i] = wsrc[i];
  }
  __syncthreads();

  int beg = offs[r0], end = offs[rEnd];
  const u32*   w1h = lw + WB_W1H;
  const float* b1  = (const float*)(lw + WB_B1);
  const u32*   w2h = lw + WB_W2H;

  for (int idx = beg + tid; idx < end; idx += 256){
    const u32* rec = perm + (size_t)idx*8;
    uint4 q0 = *reinterpret_cast<const uint4*>(rec);
    uint4 q1 = *reinterpret_cast<const uint4*>(rec + 4);
    float Y0  = bf2f((u16)(q0.x&0xffffu)), Yv0 = bf2f((u16)(q0.x>>16));
    float Yv1 = bf2f((u16)(q0.y&0xffffu)), Yv2 = bf2f((u16)(q0.y>>16));
    float re[8];
    re[0]=bf2f((u16)(q0.z&0xffffu)); re[1]=bf2f((u16)(q0.z>>16));
    re[2]=bf2f((u16)(q0.w&0xffffu)); re[3]=bf2f((u16)(q0.w>>16));
    re[4]=bf2f((u16)(q1.x&0xffffu)); re[5]=bf2f((u16)(q1.x>>16));
    re[6]=bf2f((u16)(q1.y&0xffffu)); re[7]=bf2f((u16)(q1.y>>16));
    int snd = (int)q1.z;
    int bin = (int)q1.w - r0;
    float* bp = bins + bin*BINW;

    h2 reh[4];
    #pragma unroll
    for (int ip=0;ip<4;ip++){ reh[ip].x = (_Float16)re[2*ip]; reh[ip].y = (_Float16)re[2*ip+1]; }

    // hidden layer: weights broadcast from LDS (all lanes same address)
    h2 hp[32];
    #pragma unroll
    for (int jp=0;jp<32;jp++){
      float a0 = b1[2*jp], a1 = b1[2*jp+1];
      #pragma unroll
      for (int ip=0;ip<4;ip++){
        a0 = dot2(reh[ip], w1h[(2*jp)*4+ip], a0);
        a1 = dot2(reh[ip], w1h[(2*jp+1)*4+ip], a1);
      }
      a0 = a0 * sigmoidf_(a0);
      a1 = a1 * sigmoidf_(a1);
      hp[jp].x = (_Float16)a0; hp[jp].y = (_Float16)a1;
    }

    #pragma unroll
    for (int u0=0; u0<16; u0+=4){
      uint2 sq = *reinterpret_cast<const uint2*>(sp16 + (size_t)snd*16 + u0);
      float xs[4];
      xs[0]=bf2f((u16)(sq.x&0xffffu)); xs[1]=bf2f((u16)(sq.x>>16));
      xs[2]=bf2f((u16)(sq.y&0xffffu)); xs[3]=bf2f((u16)(sq.y>>16));
      const u16* vr = vp16 + (size_t)snd*48 + u0*3;
      uint2 a0 = *reinterpret_cast<const uint2*>(vr);
      uint2 a1 = *reinterpret_cast<const uint2*>(vr+4);
      uint2 a2 = *reinterpret_cast<const uint2*>(vr+8);
      float xv[12];
      xv[0]=bf2f((u16)(a0.x&0xffffu)); xv[1]=bf2f((u16)(a0.x>>16));
      xv[2]=bf2f((u16)(a0.y&0xffffu)); xv[3]=bf2f((u16)(a0.y>>16));
      xv[4]=bf2f((u16)(a1.x&0xffffu)); xv[5]=bf2f((u16)(a1.x>>16));
      xv[6]=bf2f((u16)(a1.y&0xffffu)); xv[7]=bf2f((u16)(a1.y>>16));
      xv[8]=bf2f((u16)(a2.x&0xffffu)); xv[9]=bf2f((u16)(a2.x>>16));
      xv[10]=bf2f((u16)(a2.y&0xffffu)); xv[11]=bf2f((u16)(a2.y>>16));
      #pragma unroll
      for (int k=0;k<4;k++){
        float wv[5];
        #pragma unroll
        for (int p=0;p<5;p++){
          const u32* wp = w2h + (p*16 + u0 + k)*32;   // LDS broadcast reads
          float acc = 0.f;
          #pragma unroll
          for (int jp=0;jp<32;jp++) acc = dot2(hp[jp], wp[jp], acc);
          wv[p] = acc;
        }
        float xsk = xs[k];
        float x0 = xv[3*k], x1 = xv[3*k+1], x2 = xv[3*k+2];
        int u = u0 + k;
        atomicAdd(&bp[u],      wv[0] * xsk * Y0);
        atomicAdd(&bp[16+u],   wv[1] * (x0*Yv0 + x1*Yv1 + x2*Yv2));
        float t1 = wv[2] * xsk;
        atomicAdd(&bp[32 + 0*48 + 0*16 + u], t1*Yv0);
        atomicAdd(&bp[32 + 1*48 + 0*16 + u], t1*Yv1);
        atomicAdd(&bp[32 + 2*48 + 0*16 + u], t1*Yv2);
        float t2 = wv[3] * Y0;
        atomicAdd(&bp[32 + 0*48 + 1*16 + u], t2*x0);
        atomicAdd(&bp[32 + 1*48 + 1*16 + u], t2*x1);
        atomicAdd(&bp[32 + 2*48 + 1*16 + u], t2*x2);
        float w4 = wv[4];
        atomicAdd(&bp[32 + 0*48 + 2*16 + u], w4*(x1*Yv2 - x2*Yv1));
        atomicAdd(&bp[32 + 1*48 + 2*16 + u], w4*(x2*Yv0 - x0*Yv2));
        atomicAdd(&bp[32 + 2*48 + 2*16 + u], w4*(x0*Yv1 - x1*Yv0));
      }
    }
  }
  __syncthreads();

  // ---- fused node_post: stage 1 (scalar channel + gates) ----
  if (tid < RPB){
    int nn = r0 + tid;
    if (nn < N_NODES){
      float* bin = bins + tid*BINW;
      int sp = species[nn];
      const float* wos = wbuf + WB_WOS;
      const float* scs = wbuf + WB_SCS + sp*512;
      float ns[16];
      #pragma unroll
      for (int u=0;u<16;u++) ns[u] = ldx(ns_g, (long long)nn*16+u, isf);
      float ps[32];
      #pragma unroll
      for (int w=0;w<32;w++) ps[w]=0.f;
      #pragma unroll
      for (int u=0;u<32;u++){
        float au = bin[u]*0.25f;
        #pragma unroll
        for (int w=0;w<32;w++) ps[w] += au*wos[u*32+w];
      }
      #pragma unroll
      for (int u=0;u<16;u++){
        float nu = ns[u];
        #pragma unroll
        for (int w=0;w<32;w++) ps[w] += nu*scs[u*32+w];
      }
      if (isf){
        float* orow = (float*)out + (size_t)nn*64;
        #pragma unroll
        for (int k=0;k<16;k++){ float x=ps[k]; orow[k] = x*sigmoidf_(x) + ns[k]; }
      } else {
        u16* orow = (u16*)out + (size_t)nn*64;
        #pragma unroll
        for (int k=0;k<16;k++){ float x=ps[k]; orow[k] = f2bf(x*sigmoidf_(x) + ns[k]); }
      }
      #pragma unroll
      for (int k=0;k<16;k++) bin[k] = sigmoidf_(ps[16+k]);   // stash gates
    }
  }
  __syncthreads();

  // ---- stage 2: vector channels (node, c) ----
  if (tid < RPB*3){
    int ni = tid / 3, c = tid - ni*3;
    int nn = r0 + ni;
    if (nn < N_NODES){
      float* bin = bins + ni*BINW;
      int sp = species[nn];
      const float* wov = wbuf + WB_WOV;
      const float* scv = wbuf + WB_SCV + sp*256;
      float vin[16];
      #pragma unroll
      for (int u=0;u<16;u++) vin[u] = ldx(nv_g, (long long)nn*48 + u*3 + c, isf);
      float pv[16];
      #pragma unroll
      for (int w=0;w<16;w++) pv[w]=0.f;
      #pragma unroll
      for (int j=0;j<48;j++){
        float aj = bin[32 + c*48 + j]*0.25f;
        #pragma unroll
        for (int w=0;w<16;w++) pv[w] += aj*wov[j*16+w];
      }
      #pragma unroll
      for (int u=0;u<16;u++){
        float bu = vin[u];
        #pragma unroll
        for (int w=0;w<16;w++) pv[w] += bu*scv[u*16+w];
      }
      if (isf){
        float* orow = (float*)out + (size_t)nn*64;
        #pragma unroll
        for (int w=0;w<16;w++) orow[16 + w*3 + c] = pv[w]*bin[w] + vin[w];
      } else {
        u16* orow = (u16*)out + (size_t)nn*64;
        #pragma unroll
        for (int w=0;w<16;w++) orow[16 + w*3 + c] = f2bf(pv[w]*bin[w] + vin[w]);
      }
    }
  }
}

extern "C" void kernel_launch(void* const* d_in, const int* in_sizes, int n_in,
                              void* d_out, int out_size, void* d_ws, size_t ws_size,
                              hipStream_t stream){
  const void* node_scalars = d_in[0];
  const void* node_vectors = d_in[1];
  const void* edge_sh      = d_in[2];
  const void* radial_emb   = d_in[3];
  const int* senders      = (const int*)d_in[4];
  const int* receivers    = (const int*)d_in[5];
  const int* species      = (const int*)d_in[6];
  const void* W_in_s  = d_in[7];
  const void* W_in_v  = d_in[8];
  const void* mlp_w1  = d_in[9];
  const void* mlp_b1  = d_in[10];
  const void* mlp_w2  = d_in[11];
  const void* W_out_s = d_in[12];
  const void* W_out_v = d_in[13];
  const void* sc_s    = d_in[14];
  const void* sc_v    = d_in[15];

  float* wsf  = (float*)d_ws;
  int*   wsi  = (int*)d_ws;
  u32*   wsu  = (u32*)d_ws;
  float* wbuf = wsf + OFF_WBUF;
  u16*   sp16 = (u16*)(wsu + OFF_SP16);
  u16*   vp16 = (u16*)(wsu + OFF_VP16);
  int*   deg  = wsi + IDX_DEG;
  int*   offs = wsi + IDX_OFFS;
  int*   curs = wsi + IDX_CURS;
  u32*   perm = wsu + IDX_PERM;
  int*   flag = (int*)(wbuf + WB_FLAG);

  detect_dtype<<<1,1,0,stream>>>((const u32*)radial_emb, flag);
  hipMemsetAsync(deg, 0, (size_t)N_NODES*sizeof(int), stream);
  prep_weights<<<1,256,0,stream>>>(mlp_w1, mlp_b1, mlp_w2, W_in_s, W_in_v,
                                   W_out_s, W_out_v, sc_s, sc_v, wbuf, flag);
  node_pre<<<(N_NODES+255)/256,256,0,stream>>>(node_scalars, node_vectors, wbuf,
                                               sp16, vp16, flag);
  count_edges<<<(N_EDGES+255)/256,256,0,stream>>>(receivers, deg);
  scan_offsets<<<1,1024,0,stream>>>(deg, offs, curs);
  fill_perm<<<(N_EDGES+255)/256,256,0,stream>>>(edge_sh, radial_emb, senders, receivers,
                                                curs, perm, flag);
  fused_gather<<<(N_NODES+RPB-1)/RPB,256,0,stream>>>(perm, offs, sp16, vp16,
                                                     node_scalars, node_vectors, species,
                                                     wbuf, d_out, flag);
}

// Round 9
// 1103.260 us; speedup vs baseline: 1.7558x; 1.7558x over previous
//
#include <hip/hip_runtime.h>
#include <hip/hip_bf16.h>

typedef unsigned short u16;
typedef unsigned int   u32;
typedef _Float16 h2 __attribute__((ext_vector_type(2)));
typedef short s8v __attribute__((ext_vector_type(8)));
typedef float f4v __attribute__((ext_vector_type(4)));

#define N_NODES 50000
#define N_EDGES 800000
#define NCH   4
#define RPC   12500      // receivers per chunk
#define CHMAX 204800     // max edges per chunk (mean 200k, +12 sigma)
#define BINW  177

// ---- ws layout (u32 units), total 10,750,264 u32 = 43.0 MB ----
#define WB_W1H  0        // [64][4] u32 half2 (fp16 pairs of W1 columns)
#define WB_B1   256      // [64] f32
#define WB_W2F  320      // 5120 bf16 = 2560 u32, MFMA B-frag layout
#define WB_WINS 2880
#define WB_WINV 3136
#define WB_WOS  3392
#define WB_WOV  4416
#define WB_SCS  5184
#define WB_SCV  7232
#define WB_FLAG 8256
#define OFF_SP16 8260    // 800,000 u16
#define OFF_VP16 408260  // 2,400,000 u16
#define IDX_DEG  1608260
#define IDX_OFFS 1658260
#define IDX_CURS 1708262
#define IDX_BUCK 1758262 // 800,000 int
#define OFF_WP   2558264 // 5 planes x CHMAX*16 u16 = 8,192,000 u32

__device__ __forceinline__ float bf2f(u16 v){
  union { u32 u; float f; } x; x.u = ((u32)v) << 16; return x.f;
}
__device__ __forceinline__ u16 f2bf(float f){
  u32 u = __float_as_uint(f);
  u32 lsb = (u >> 16) & 1u;
  u32 r = u + 0x7fffu + lsb;
  return (u16)(r >> 16);
}
__device__ __forceinline__ float ldx(const void* p, long long i, int isf){
  return isf ? ((const float*)p)[i] : bf2f(((const u16*)p)[i]);
}
__device__ __forceinline__ u32 pkh2(float a, float b){
  union { u32 u; h2 v; } x; x.v.x = (_Float16)a; x.v.y = (_Float16)b; return x.u;
}
__device__ __forceinline__ float dot2(h2 a, u32 w, float c){
  union { u32 u; h2 v; } x; x.u = w;
#if __has_builtin(__builtin_amdgcn_fdot2)
  return __builtin_amdgcn_fdot2(a, x.v, c, false);
#else
  return c + (float)a.x*(float)x.v.x + (float)a.y*(float)x.v.y;
#endif
}
__device__ __forceinline__ float sigmoidf_(float x){ return 1.f/(1.f + __expf(-x)); }

__global__ void detect_dtype(const u32* __restrict__ remb_raw, int* __restrict__ flag){
  int isf32 = 0;
  for (int k = 0; k < 64; k++){
    u32 w = remb_raw[k];
    u32 lo = w & 0xffffu, hi = w >> 16;
    int okl = ((lo & 0x8000u) == 0) && (((lo >> 7) & 0xffu) <= 126u);
    int okh = ((hi & 0x8000u) == 0) && (((hi >> 7) & 0xffu) <= 126u);
    if (!(okl && okh)) isf32 = 1;
  }
  *flag = isf32;
}

__global__ void prep_weights(const void* __restrict__ w1, const void* __restrict__ b1g,
                             const void* __restrict__ w2, const void* __restrict__ wins,
                             const void* __restrict__ winv, const void* __restrict__ wos,
                             const void* __restrict__ wov, const void* __restrict__ scs,
                             const void* __restrict__ scv, float* __restrict__ wbuf,
                             const int* __restrict__ flag){
  int t = threadIdx.x;
  int isf = *flag;
  u32* w1h  = (u32*)(wbuf + WB_W1H);
  u16* w2f  = (u16*)(wbuf + WB_W2F);
  for (int idx=t; idx<256;  idx+=256){
    int j = idx>>2, ip = idx&3;
    w1h[idx] = pkh2(ldx(w1, (2*ip)*64+j, isf), ldx(w1, (2*ip+1)*64+j, isf));
  }
  for (int idx=t; idx<64;   idx+=256){ wbuf[WB_B1+idx]  = ldx(b1g, idx, isf); }
  // MFMA B-frag layout for 16x16x32 bf16: lane holds B[k=(lane>>4)*8+j][n=lane&15]
  for (int idx=t; idx<5120; idx+=256){
    int tt = idx >> 10;           // N-tile 0..4
    int rem = idx & 1023;
    int kh = rem >> 9;            // K-half 0..1
    int rem2 = rem & 511;
    int ln = rem2 >> 3, j = rem2 & 7;
    int k = kh*32 + (ln>>4)*8 + j;
    int o = tt*16 + (ln&15);
    w2f[idx] = f2bf(ldx(w2, (long long)k*80 + o, isf));
  }
  for (int idx=t; idx<256;  idx+=256){ wbuf[WB_WINS+idx] = ldx(wins, idx, isf); }
  for (int idx=t; idx<256;  idx+=256){ wbuf[WB_WINV+idx] = ldx(winv, idx, isf); }
  for (int idx=t; idx<1024; idx+=256){ wbuf[WB_WOS+idx]  = ldx(wos, idx, isf); }
  for (int idx=t; idx<768;  idx+=256){ wbuf[WB_WOV+idx]  = ldx(wov, idx, isf); }
  for (int idx=t; idx<2048; idx+=256){ wbuf[WB_SCS+idx]  = ldx(scs, idx, isf); }
  for (int idx=t; idx<1024; idx+=256){ wbuf[WB_SCV+idx]  = ldx(scv, idx, isf); }
}

__global__ void node_pre(const void* __restrict__ ns_g, const void* __restrict__ nv_g,
                         const float* __restrict__ wbuf, u16* __restrict__ sp16,
                         u16* __restrict__ vp16, const int* __restrict__ flag){
  int n = blockIdx.x*256 + threadIdx.x;
  if (n >= N_NODES) return;
  int isf = *flag;
  float a[16], b[48];
  #pragma unroll
  for (int u=0;u<16;u++) a[u] = ldx(ns_g, n*16+u, isf);
  #pragma unroll
  for (int u=0;u<48;u++) b[u] = ldx(nv_g, n*48+u, isf);
  const float* wins = wbuf + WB_WINS;
  const float* winv = wbuf + WB_WINV;
  float s[16];
  #pragma unroll
  for (int w=0;w<16;w++) s[w]=0.f;
  #pragma unroll
  for (int u=0;u<16;u++){
    float au = a[u];
    #pragma unroll
    for (int w=0;w<16;w++) s[w] += au * wins[u*16+w];
  }
  #pragma unroll
  for (int w=0;w<16;w++) sp16[n*16+w] = f2bf(s[w]);
  float v0[16], v1[16], v2[16];
  #pragma unroll
  for (int w=0;w<16;w++){ v0[w]=0.f; v1[w]=0.f; v2[w]=0.f; }
  #pragma unroll
  for (int u=0;u<16;u++){
    float bu0=b[u*3], bu1=b[u*3+1], bu2=b[u*3+2];
    #pragma unroll
    for (int w=0;w<16;w++){
      float wv = winv[u*16+w];
      v0[w] += bu0*wv; v1[w] += bu1*wv; v2[w] += bu2*wv;
    }
  }
  #pragma unroll
  for (int w=0;w<16;w++){
    vp16[n*48+w*3]   = f2bf(v0[w]);
    vp16[n*48+w*3+1] = f2bf(v1[w]);
    vp16[n*48+w*3+2] = f2bf(v2[w]);
  }
}

__global__ void count_edges(const int* __restrict__ receivers, int* __restrict__ deg){
  int e = blockIdx.x*256 + threadIdx.x;
  if (e < N_EDGES) atomicAdd(&deg[receivers[e]], 1);
}

__global__ void scan_offsets(const int* __restrict__ deg, int* __restrict__ offs,
                             int* __restrict__ curs){
  __shared__ int part[1024];
  int t = threadIdx.x;
  const int PER = 49;
  int base = t*PER;
  int s = 0;
  for (int i=0;i<PER;i++){ int n=base+i; if (n<N_NODES) s += deg[n]; }
  part[t] = s; __syncthreads();
  for (int off=1; off<1024; off<<=1){
    int v = (t>=off) ? part[t-off] : 0;
    __syncthreads(); part[t] += v; __syncthreads();
  }
  int run = (t==0) ? 0 : part[t-1];
  for (int i=0;i<PER;i++){
    int n=base+i;
    if (n<N_NODES){ offs[n]=run; curs[n]=run; run += deg[n]; }
  }
  if (t==1023) offs[N_NODES] = run;
}

__global__ void fill_bucket(const int* __restrict__ receivers, int* __restrict__ curs,
                            int* __restrict__ bucket){
  int e = blockIdx.x*256 + threadIdx.x;
  if (e < N_EDGES){
    int p = atomicAdd(&curs[receivers[e]], 1);
    bucket[p] = e;
  }
}

// pass1: per chunk, compute w[80] per edge via MFMA. wave = 16 edges.
__global__ void __launch_bounds__(256) pass1_w(
    const int* __restrict__ bucket, const int* __restrict__ offs,
    const void* __restrict__ remb, const float* __restrict__ wbuf,
    u16* __restrict__ wp16, int rlo, const int* __restrict__ flag){
  __shared__ u16 hlds[4*16*72];        // 4 waves x 16 edges x 64 h (+8 pad)
  int tid = threadIdx.x;
  int lane = tid & 63, wid = tid >> 6;
  int isf = *flag;
  int chunkBeg = offs[rlo], chunkEnd = offs[rlo + RPC];
  int r0e = chunkBeg + (blockIdx.x*4 + wid)*16;
  if (r0e >= chunkEnd) return;         // whole-wave exit; no __syncthreads in kernel
  u16* hw = hlds + wid*(16*72);
  int e = lane & 15, q = lane >> 4;

  // ---- h for edge (r0e+e), j = q*16 .. q*16+15 ----
  int er = r0e + e;
  int eid = (er < chunkEnd) ? bucket[er] : 0;
  float re[8];
  #pragma unroll
  for (int i=0;i<8;i++) re[i] = ldx(remb, (long long)eid*8+i, isf);
  h2 reh[4];
  #pragma unroll
  for (int ip=0;ip<4;ip++){ reh[ip].x=(_Float16)re[2*ip]; reh[ip].y=(_Float16)re[2*ip+1]; }
  const u32* w1h = (const u32*)(wbuf + WB_W1H);
  const float* b1 = wbuf + WB_B1;
  #pragma unroll
  for (int jj=0;jj<16;jj++){
    int j = q*16 + jj;
    float a = b1[j];
    #pragma unroll
    for (int ip=0;ip<4;ip++) a = dot2(reh[ip], w1h[j*4+ip], a);
    a = a * sigmoidf_(a);
    hw[e*72 + j] = f2bf(a);
  }
  asm volatile("s_waitcnt lgkmcnt(0)" ::: "memory");  // wave-local LDS exchange

  // ---- B-frags (W2), 10 x 16B, coalesced, held in VGPRs ----
  const u16* w2f = (const u16*)(wbuf + WB_W2F);
  s8v bfr[5][2];
  #pragma unroll
  for (int t=0;t<5;t++)
    #pragma unroll
    for (int kh=0;kh<2;kh++)
      bfr[t][kh] = *(const s8v*)(w2f + ((t*2+kh)*64 + lane)*8);

  f4v acc[5];
  #pragma unroll
  for (int t=0;t<5;t++) acc[t] = (f4v){0.f,0.f,0.f,0.f};
  #pragma unroll
  for (int kh=0;kh<2;kh++){
    // A-frag: lane holds h[m=lane&15][k=kh*32 + q*8 + j]
    s8v af = *(const s8v*)(hw + e*72 + kh*32 + q*8);
    #pragma unroll
    for (int t=0;t<5;t++)
      acc[t] = __builtin_amdgcn_mfma_f32_16x16x32_bf16(af, bfr[t][kh], acc[t], 0,0,0);
  }
  // ---- store: C layout col=lane&15 (=u), row=q*4+reg (=edge in tile) ----
  int n = lane & 15;
  #pragma unroll
  for (int r=0;r<4;r++){
    int er2 = r0e + q*4 + r;
    if (er2 < chunkEnd){
      int widx = er2 - chunkBeg;
      #pragma unroll
      for (int t=0;t<5;t++)
        wp16[(size_t)t*(CHMAX*16) + (size_t)widx*16 + n] = f2bf(acc[t][r]);
    }
  }
}

// pass2: per chunk, receiver-major register reduction + fused epilogue. no atomics.
__global__ void __launch_bounds__(256) pass2_reduce(
    const int* __restrict__ bucket, const int* __restrict__ offs,
    const void* __restrict__ edge_sh, const int* __restrict__ senders,
    const u16* __restrict__ sp16, const u16* __restrict__ vp16,
    const u16* __restrict__ wp16, const float* __restrict__ wbuf,
    const void* __restrict__ ns_g, const void* __restrict__ nv_g,
    const int* __restrict__ species, void* __restrict__ out,
    int rlo, const int* __restrict__ flag){
  __shared__ float bins[16*BINW];
  int tid = threadIdx.x;
  int isf = *flag;
  int grp = tid >> 4, u = tid & 15;
  int r0n = rlo + blockIdx.x*16;
  int r = r0n + grp;
  int rhi = rlo + RPC;
  int chunkBeg = offs[rlo];
  int beg=0, end=0;
  if (r < rhi){ beg = offs[r]; end = offs[r+1]; }
  float As0=0,As1=0;
  float Av00=0,Av01=0,Av02=0, Av10=0,Av11=0,Av12=0, Av20=0,Av21=0,Av22=0;
  for (int rank=beg; rank<end; rank++){
    int eid = bucket[rank];
    float Y0  = ldx(edge_sh,(long long)eid*4+0,isf);
    float Yv0 = ldx(edge_sh,(long long)eid*4+1,isf);
    float Yv1 = ldx(edge_sh,(long long)eid*4+2,isf);
    float Yv2 = ldx(edge_sh,(long long)eid*4+3,isf);
    int snd = senders[eid];
    size_t widx = (size_t)(rank - chunkBeg)*16 + u;
    float w0 = bf2f(wp16[widx]);
    float w1 = bf2f(wp16[(size_t)1*(CHMAX*16) + widx]);
    float w2 = bf2f(wp16[(size_t)2*(CHMAX*16) + widx]);
    float w3 = bf2f(wp16[(size_t)3*(CHMAX*16) + widx]);
    float w4 = bf2f(wp16[(size_t)4*(CHMAX*16) + widx]);
    float xs = bf2f(sp16[(size_t)snd*16 + u]);
    float x0 = bf2f(vp16[(size_t)snd*48 + u*3 + 0]);
    float x1 = bf2f(vp16[(size_t)snd*48 + u*3 + 1]);
    float x2 = bf2f(vp16[(size_t)snd*48 + u*3 + 2]);
    As0 += w0*xs*Y0;
    As1 += w1*(x0*Yv0 + x1*Yv1 + x2*Yv2);
    float t1 = w2*xs;  Av00 += t1*Yv0; Av01 += t1*Yv1; Av02 += t1*Yv2;
    float t2 = w3*Y0;  Av10 += t2*x0;  Av11 += t2*x1;  Av12 += t2*x2;
    Av20 += w4*(x1*Yv2 - x2*Yv1);
    Av21 += w4*(x2*Yv0 - x0*Yv2);
    Av22 += w4*(x0*Yv1 - x1*Yv0);
  }
  float* bp = bins + grp*BINW;
  bp[u] = As0; bp[16+u] = As1;
  bp[32+0*48+0*16+u]=Av00; bp[32+1*48+0*16+u]=Av01; bp[32+2*48+0*16+u]=Av02;
  bp[32+0*48+1*16+u]=Av10; bp[32+1*48+1*16+u]=Av11; bp[32+2*48+1*16+u]=Av12;
  bp[32+0*48+2*16+u]=Av20; bp[32+1*48+2*16+u]=Av21; bp[32+2*48+2*16+u]=Av22;
  __syncthreads();

  // ---- stage 1: scalar channel + gates ----
  if (tid < 16){
    int nn = r0n + tid;
    if (nn < rhi && nn < N_NODES){
      float* bin = bins + tid*BINW;
      int sp = species[nn];
      const float* wos = wbuf + WB_WOS;
      const float* scs = wbuf + WB_SCS + sp*512;
      float ns[16];
      #pragma unroll
      for (int uu=0;uu<16;uu++) ns[uu] = ldx(ns_g, (long long)nn*16+uu, isf);
      float ps[32];
      #pragma unroll
      for (int w=0;w<32;w++) ps[w]=0.f;
      #pragma unroll
      for (int uu=0;uu<32;uu++){
        float au = bin[uu]*0.25f;
        #pragma unroll
        for (int w=0;w<32;w++) ps[w] += au*wos[uu*32+w];
      }
      #pragma unroll
      for (int uu=0;uu<16;uu++){
        float nu = ns[uu];
        #pragma unroll
        for (int w=0;w<32;w++) ps[w] += nu*scs[uu*32+w];
      }
      if (isf){
        float* orow = (float*)out + (size_t)nn*64;
        #pragma unroll
        for (int k=0;k<16;k++){ float x=ps[k]; orow[k] = x*sigmoidf_(x) + ns[k]; }
      } else {
        u16* orow = (u16*)out + (size_t)nn*64;
        #pragma unroll
        for (int k=0;k<16;k++){ float x=ps[k]; orow[k] = f2bf(x*sigmoidf_(x) + ns[k]); }
      }
      #pragma unroll
      for (int k=0;k<16;k++) bin[k] = sigmoidf_(ps[16+k]);   // stash gates
    }
  }
  __syncthreads();

  // ---- stage 2: vector channels ----
  if (tid < 48){
    int ni = tid / 3, c = tid - ni*3;
    int nn = r0n + ni;
    if (nn < rhi && nn < N_NODES){
      float* bin = bins + ni*BINW;
      int sp = species[nn];
      const float* wov = wbuf + WB_WOV;
      const float* scv = wbuf + WB_SCV + sp*256;
      float vin[16];
      #pragma unroll
      for (int uu=0;uu<16;uu++) vin[uu] = ldx(nv_g, (long long)nn*48 + uu*3 + c, isf);
      float pv[16];
      #pragma unroll
      for (int w=0;w<16;w++) pv[w]=0.f;
      #pragma unroll
      for (int j=0;j<48;j++){
        float aj = bin[32 + c*48 + j]*0.25f;
        #pragma unroll
        for (int w=0;w<16;w++) pv[w] += aj*wov[j*16+w];
      }
      #pragma unroll
      for (int uu=0;uu<16;uu++){
        float bu = vin[uu];
        #pragma unroll
        for (int w=0;w<16;w++) pv[w] += bu*scv[uu*16+w];
      }
      if (isf){
        float* orow = (float*)out + (size_t)nn*64;
        #pragma unroll
        for (int w=0;w<16;w++) orow[16 + w*3 + c] = pv[w]*bin[w] + vin[w];
      } else {
        u16* orow = (u16*)out + (size_t)nn*64;
        #pragma unroll
        for (int w=0;w<16;w++) orow[16 + w*3 + c] = f2bf(pv[w]*bin[w] + vin[w]);
      }
    }
  }
}

extern "C" void kernel_launch(void* const* d_in, const int* in_sizes, int n_in,
                              void* d_out, int out_size, void* d_ws, size_t ws_size,
                              hipStream_t stream){
  const void* node_scalars = d_in[0];
  const void* node_vectors = d_in[1];
  const void* edge_sh      = d_in[2];
  const void* radial_emb   = d_in[3];
  const int* senders      = (const int*)d_in[4];
  const int* receivers    = (const int*)d_in[5];
  const int* species      = (const int*)d_in[6];
  const void* W_in_s  = d_in[7];
  const void* W_in_v  = d_in[8];
  const void* mlp_w1  = d_in[9];
  const void* mlp_b1  = d_in[10];
  const void* mlp_w2  = d_in[11];
  const void* W_out_s = d_in[12];
  const void* W_out_v = d_in[13];
  const void* sc_s    = d_in[14];
  const void* sc_v    = d_in[15];

  float* wsf  = (float*)d_ws;
  int*   wsi  = (int*)d_ws;
  u32*   wsu  = (u32*)d_ws;
  float* wbuf = wsf;
  u16*   sp16 = (u16*)(wsu + OFF_SP16);
  u16*   vp16 = (u16*)(wsu + OFF_VP16);
  int*   deg  = wsi + IDX_DEG;
  int*   offs = wsi + IDX_OFFS;
  int*   curs = wsi + IDX_CURS;
  int*   buck = wsi + IDX_BUCK;
  u16*   wp16 = (u16*)(wsu + OFF_WP);
  int*   flag = (int*)(wbuf + WB_FLAG);

  detect_dtype<<<1,1,0,stream>>>((const u32*)radial_emb, flag);
  hipMemsetAsync(deg, 0, (size_t)N_NODES*sizeof(int), stream);
  prep_weights<<<1,256,0,stream>>>(mlp_w1, mlp_b1, mlp_w2, W_in_s, W_in_v,
                                   W_out_s, W_out_v, sc_s, sc_v, wbuf, flag);
  node_pre<<<(N_NODES+255)/256,256,0,stream>>>(node_scalars, node_vectors, wbuf,
                                               sp16, vp16, flag);
  count_edges<<<(N_EDGES+255)/256,256,0,stream>>>(receivers, deg);
  scan_offsets<<<1,1024,0,stream>>>(deg, offs, curs);
  fill_bucket<<<(N_EDGES+255)/256,256,0,stream>>>(receivers, curs, buck);
  for (int c = 0; c < NCH; c++){
    int rlo = c * RPC;
    pass1_w<<<CHMAX/64, 256, 0, stream>>>(buck, offs, radial_emb, wbuf, wp16, rlo, flag);
    pass2_reduce<<<(RPC+15)/16, 256, 0, stream>>>(buck, offs, edge_sh, senders,
                                                  sp16, vp16, wp16, wbuf,
                                                  node_scalars, node_vectors, species,
                                                  d_out, rlo, flag);
  }
}